// Round 8
// baseline (275.332 us; speedup 1.0000x reference)
//
#include <hip/hip_runtime.h>
#include <hip/hip_bf16.h>
#include <math.h>

#define HIDDEN 1024
#define ADIM 32
#define NEMB 32
#define BB 128
#define TT 16
#define NROWS (BB*TT)   // 2048

typedef float f32x4 __attribute__((ext_vector_type(4)));
typedef short bf16x8 __attribute__((ext_vector_type(8)));
typedef unsigned short u16;

static __device__ __forceinline__ u16 f2bf(float f) {
    union { __hip_bfloat16 h; u16 u; } cv;
    cv.h = __float2bfloat16(f);   // RNE
    return cv.u;
}

// ws layout:
//  [0, 4096)   : meta ints: [0..31]=cnt, [32..63]=off, [64..191]=blist,
//                [192]=ntiles, [200+4i..]=tiles (row0, rows, e)
//  xg  @ 4096  : 2048 x 2048 bf16 (8MB), grouped rows
//  yg  @ +8MB  : 2048 x 1024 bf16 (4MB), grouped rows

__global__ void prep_kernel(const int* __restrict__ cat, int* __restrict__ meta) {
    __shared__ int c[BB];
    int tid = threadIdx.x;
    if (tid < BB) c[tid] = cat[tid];
    __syncthreads();
    if (tid == 0) {
        int cnt[NEMB];
        for (int e = 0; e < NEMB; e++) cnt[e] = 0;
        for (int b = 0; b < BB; b++) cnt[c[b]]++;
        int off = 0;
        for (int e = 0; e < NEMB; e++) { meta[e] = cnt[e]; meta[32 + e] = off; off += cnt[e]; }
        int pos[NEMB];
        for (int e = 0; e < NEMB; e++) pos[e] = meta[32 + e];
        for (int b = 0; b < BB; b++) { int e = c[b]; meta[64 + pos[e]] = b; pos[e]++; }
        int nt = 0;
        for (int e = 0; e < NEMB; e++) {
            int Me = cnt[e] * TT;
            int base = meta[32 + e] * TT;
            for (int mb = 0; mb * 64 < Me; mb++) {
                int rows = Me - mb * 64; if (rows > 64) rows = 64;
                meta[200 + 4 * nt + 0] = base + mb * 64;
                meta[200 + 4 * nt + 1] = rows;
                meta[200 + 4 * nt + 2] = e;
                nt++;
            }
        }
        meta[192] = nt;   // <= 56
    }
}

// Layer 1 + PE, written grouped as bf16.
__global__ __launch_bounds__(256) void build_x_kernel(
    const float* __restrict__ actions, const int* __restrict__ timesteps,
    const int* __restrict__ cat_ids, const float* __restrict__ W1,
    const float* __restrict__ b1, const int* __restrict__ meta,
    u16* __restrict__ xg)
{
    int sb = blockIdx.x;
    int b  = meta[64 + sb];
    int e  = cat_ids[b];
    int tid = threadIdx.x;

    __shared__ float act[TT][ADIM];
    for (int i = tid; i < TT * ADIM; i += 256)
        act[i / ADIM][i % ADIM] = actions[(size_t)b * TT * ADIM + i];
    __syncthreads();

    float tau = (float)timesteps[b];

    for (int h = tid; h < HIDDEN; h += 256) {
        float acc[TT];
        #pragma unroll
        for (int t = 0; t < TT; t++) acc[t] = 0.f;
        for (int d = 0; d < ADIM; d++) {
            float w = W1[((size_t)e * ADIM + d) * HIDDEN + h];
            #pragma unroll
            for (int t = 0; t < TT; t++) acc[t] += act[t][d] * w;
        }
        float bv = b1[(size_t)e * HIDDEN + h];
        for (int t = 0; t < TT; t++)
            xg[(size_t)(sb * TT + t) * 2048 + h] = f2bf(acc[t] + bv);
    }

    for (int j = tid; j < HIDDEN; j += 256) {
        int i = j >> 1;
        float arg = tau * expf((float)i * -0.017988946f);
        float v = (j & 1) ? cosf(arg) : sinf(arg);
        u16 bv = f2bf(v);
        for (int t = 0; t < TT; t++)
            xg[(size_t)(sb * TT + t) * 2048 + 1024 + j] = bv;
    }
}

// No-LDS, no-barrier, wave-private direct-fragment grouped GEMM.
// grid 1D: bid = nq(16) + 16*slot. Block 256 = 4 independent waves, each
// owning a 32m x 32n quadrant of the 64x64 tile. B-fragments are gathered
// directly from W f32 with per-lane dword loads in MFMA fragment layout
// (lane: n = l&15, k-run = (l>>4)*8 + r); A-fragments load from bf16 xg.
// 2-deep ping-pong, branch-free steady loop -> precisely counted vmcnt
// waits, zero barriers, zero LDS. Waves free-run at HBM pace.
// mode 0: +bias, swish, bf16 store grouped. mode 1: +bias, f32 natural scatter.
__global__ __launch_bounds__(256, 4) void gemm_direct(
    const u16* __restrict__ X,        // grouped rows bf16, ld = ldx
    const float* __restrict__ W,      // (NEMB, Kdim, 1024) f32
    const float* __restrict__ bias,   // (NEMB, 1024) f32
    void* __restrict__ outp,
    const int* __restrict__ meta,
    int Kdim, int ldx, int mode)
{
    int bid  = blockIdx.x;
    int nq   = bid & 15;
    int slot = bid >> 4;
    if (slot >= meta[192]) return;
    int row0      = meta[200 + 4 * slot + 0];
    int rowsValid = meta[200 + 4 * slot + 1];
    int e         = meta[200 + 4 * slot + 2];

    int tid  = threadIdx.x;
    int lane = tid & 63;
    int wid  = tid >> 6;
    int wm   = wid & 1;            // m-half (32 rows)
    int wn   = wid >> 1;           // n-half (32 cols)
    int l15  = lane & 15;
    int kh   = lane >> 4;          // k-run group (0..3)
    int n0   = nq * 64 + wn * 32;  // wave's 32-col base

    const float* Wp = W + (size_t)e * Kdim * 1024;

    // B gather offsets (f32 elements), r = 0..7 within the lane's k-run;
    // fragment s=1 is +16 elements (64B immediate).
    unsigned bo[8];
    #pragma unroll
    for (int r = 0; r < 8; r++)
        bo[r] = (unsigned)((kh * 8 + r) * 1024 + n0 + l15);
    // A offsets (u16 elements), fragment f = 0,1 (rows clamped in-bounds;
    // invalid rows only feed unstored outputs)
    unsigned ao[2];
    #pragma unroll
    for (int f = 0; f < 2; f++) {
        int m = row0 + wm * 32 + f * 16 + l15;
        if (m > NROWS - 1) m = NROWS - 1;
        ao[f] = (unsigned)(m * ldx + kh * 8);
    }

    float  bgA[2][8], bgB[2][8];   // [s][r] raw f32, ping-pong
    bf16x8 agA[2], agB[2];         // A frags, ping-pong

    f32x4 acc[2][2];               // [f][s]
    #pragma unroll
    for (int f = 0; f < 2; f++)
        #pragma unroll
        for (int s = 0; s < 2; s++)
            acc[f][s] = (f32x4){0.f, 0.f, 0.f, 0.f};

    #define ISSUE(bg, ag) do { \
        _Pragma("unroll") \
        for (int r = 0; r < 8; r++) { \
            bg[0][r] = Wp[bo[r]]; \
            bg[1][r] = Wp[bo[r] + 16]; \
            bo[r] += 32 * 1024; \
        } \
        _Pragma("unroll") \
        for (int f = 0; f < 2; f++) { \
            ag[f] = *(const bf16x8*)&X[ao[f]]; \
            ao[f] += 32; \
        } \
    } while (0)

    #define PROC(bg, ag) do { \
        bf16x8 bf[2]; \
        _Pragma("unroll") \
        for (int s = 0; s < 2; s++) \
            _Pragma("unroll") \
            for (int j = 0; j < 8; j++) \
                bf[s][j] = (short)f2bf(bg[s][j]); \
        _Pragma("unroll") \
        for (int f = 0; f < 2; f++) \
            _Pragma("unroll") \
            for (int s = 0; s < 2; s++) \
                acc[f][s] = __builtin_amdgcn_mfma_f32_16x16x32_bf16(ag[f], bf[s], acc[f][s], 0, 0, 0); \
    } while (0)

    int nT = Kdim >> 5;            // k-steps of 32 (64 or 32; even)

    // prologue: 2 steps in flight
    ISSUE(bgA, agA);
    ISSUE(bgB, agB);

    // branch-free steady state: waits are dependency-counted, >=18 loads
    // always in flight per wave, no barriers anywhere.
    for (int kt = 0; kt < nT - 2; kt += 2) {
        PROC(bgA, agA);
        ISSUE(bgA, agA);
        PROC(bgB, agB);
        ISSUE(bgB, agB);
    }
    PROC(bgA, agA);
    PROC(bgB, agB);

    #undef ISSUE
    #undef PROC

    // fused epilogue
    float bv[2];
    #pragma unroll
    for (int s = 0; s < 2; s++)
        bv[s] = bias[(size_t)e * 1024 + n0 + s * 16 + l15];

    #pragma unroll
    for (int f = 0; f < 2; f++) {
        #pragma unroll
        for (int r = 0; r < 4; r++) {
            int m = wm * 32 + f * 16 + kh * 4 + r;
            if (m < rowsValid) {
                int grow = row0 + m;
                if (mode == 0) {
                    u16* dst = (u16*)outp + (size_t)grow * 1024 + n0 + l15;
                    #pragma unroll
                    for (int s = 0; s < 2; s++) {
                        float h = acc[f][s][r] + bv[s];
                        h = h / (1.f + expf(-h));
                        dst[s * 16] = f2bf(h);
                    }
                } else {
                    int bnat = meta[64 + (grow >> 4)];
                    float* dst = (float*)outp + ((size_t)bnat * TT + (grow & 15)) * 1024 + n0 + l15;
                    #pragma unroll
                    for (int s = 0; s < 2; s++)
                        dst[s * 16] = acc[f][s][r] + bv[s];
                }
            }
        }
    }
}

extern "C" void kernel_launch(void* const* d_in, const int* in_sizes, int n_in,
                              void* d_out, int out_size, void* d_ws, size_t ws_size,
                              hipStream_t stream) {
    const float* actions   = (const float*)d_in[0];
    const int*   timesteps = (const int*)d_in[1];
    const int*   cat_ids   = (const int*)d_in[2];
    const float* W1        = (const float*)d_in[3];
    const float* b1        = (const float*)d_in[4];
    const float* W2        = (const float*)d_in[5];
    const float* b2        = (const float*)d_in[6];
    const float* W3        = (const float*)d_in[7];
    const float* b3        = (const float*)d_in[8];
    float* out = (float*)d_out;

    int* meta = (int*)d_ws;
    u16* xg   = (u16*)((char*)d_ws + 4096);
    u16* yg   = (u16*)((char*)d_ws + 4096 + 8ull * 1024 * 1024);

    prep_kernel<<<1, 128, 0, stream>>>(cat_ids, meta);
    build_x_kernel<<<128, 256, 0, stream>>>(actions, timesteps, cat_ids, W1, b1, meta, xg);

    // layer 2: K=2048, swish, bf16 grouped -> yg
    gemm_direct<<<896, 256, 0, stream>>>(xg, W2, b2, (void*)yg, meta, 2048, 2048, 0);
    // layer 3: K=1024, +bias, f32 natural scatter -> out
    gemm_direct<<<896, 256, 0, stream>>>(yg, W3, b3, (void*)out, meta, 1024, 1024, 1);
}